// Round 1
// baseline (2861.883 us; speedup 1.0000x reference)
//
#include <hip/hip_runtime.h>
#include <cstdint>
#include <cstddef>

#define N_NODES 100000
#define D_DIM   256
#define RAW_DIM 640
#define M_MSG   200000

typedef short bf16x8 __attribute__((ext_vector_type(8)));
typedef short bf16x4 __attribute__((ext_vector_type(4)));
typedef float f32x4  __attribute__((ext_vector_type(4)));

__device__ __forceinline__ uint16_t f2bf(float f) {
  union { float f; uint32_t u; } v; v.f = f;
  return (uint16_t)((v.u + 0x7FFFu + ((v.u >> 16) & 1u)) >> 16);
}

// ---------------- weight swizzle: W[640][256] -> MFMA B-frag order ----------
// out[ks(20)][ct(16)][lane(64)][j(8)] = W[ks*32 + (lane>>4)*8 + j][ct*16 + (lane&15)]
__global__ void prep_w(const float* __restrict__ W, uint16_t* __restrict__ out) {
  int t = blockIdx.x * 256 + threadIdx.x;       // 0..20479
  int lane = t & 63;
  int ct   = (t >> 6) & 15;
  int ks   = t >> 10;                            // 0..19
  int kb   = ks * 32 + (lane >> 4) * 8;
  int n    = ct * 16 + (lane & 15);
  bf16x8 v;
#pragma unroll
  for (int j = 0; j < 8; ++j) v[j] = (short)f2bf(W[(size_t)(kb + j) * 256 + n]);
  ((bf16x8*)out)[t] = v;
}

// ------------- Wbig[512][1024] swizzle from W_gru/U_gru [256][768] ----------
// col groups: [0,256): xr+hr  [256,512): xz+hz  [512,768): xn  [768,1024): hn
__global__ void prep_wbig(const float* __restrict__ Wg, const float* __restrict__ Ug,
                          uint16_t* __restrict__ out) {
  int t = blockIdx.x * 256 + threadIdx.x;       // 0..65535
  int lane = t & 63;
  int ct   = (t >> 6) & 63;
  int ks   = t >> 12;                            // 0..15
  int kb   = ks * 32 + (lane >> 4) * 8;
  int n    = ct * 16 + (lane & 15);              // 0..1023
  int g    = n >> 8, c = n & 255;
  bf16x8 v;
#pragma unroll
  for (int j = 0; j < 8; ++j) {
    int k = kb + j;                              // 0..511
    float x;
    if (g == 0)      x = (k < 256) ? Wg[(size_t)k * 768 + c]         : Ug[(size_t)(k - 256) * 768 + c];
    else if (g == 1) x = (k < 256) ? Wg[(size_t)k * 768 + 256 + c]   : Ug[(size_t)(k - 256) * 768 + 256 + c];
    else if (g == 2) x = (k < 256) ? Wg[(size_t)k * 768 + 512 + c]   : 0.0f;
    else             x = (k < 256) ? 0.0f                            : Ug[(size_t)(k - 256) * 768 + 512 + c];
    v[j] = (short)f2bf(x);
  }
  ((bf16x8*)out)[t] = v;
}

// ---------------- per-node message counts (float) ---------------------------
__global__ void count_k(const int* __restrict__ s_src, const int* __restrict__ d_src,
                        float* __restrict__ counts) {
  int i = blockIdx.x * 256 + threadIdx.x;
  if (i < 2 * M_MSG) {
    int node = (i < M_MSG) ? s_src[i] : d_src[i - M_MSG];
    atomicAdd(&counts[node], 1.0f);
  }
}

// ------------- msg GEMM: [2M,640]@[640,256] + bias, scatter-add to agg ------
// block = 256 thr (4 waves), tile 64 rows x 256 cols, wave w rows [w*16,w*16+16)
__global__ __launch_bounds__(256) void gemm_msg(
    const float* __restrict__ s_raw, const float* __restrict__ d_raw,
    const int* __restrict__ s_src, const int* __restrict__ d_src,
    const uint16_t* __restrict__ Wsrc_sw, const uint16_t* __restrict__ Wdst_sw,
    const float* __restrict__ b_src, const float* __restrict__ b_dst,
    float* __restrict__ agg) {
  const int b = blockIdx.x;
  const bool is_s = b < (M_MSG / 64);
  const float*    raw  = is_s ? s_raw : d_raw;
  const int*      src  = is_s ? s_src : d_src;
  const uint16_t* Wsw  = is_s ? Wsrc_sw : Wdst_sw;
  const float*    bias = is_s ? b_src : b_dst;
  const int row0 = (is_s ? b : b - M_MSG / 64) * 64;

  __shared__ uint16_t As[64][40];               // 64 rows x 32 k (bf16), pad->40

  const int t    = threadIdx.x;
  const int lane = t & 63;
  const int w    = t >> 6;
  const int quad = lane >> 4;
  const int l15  = lane & 15;

  f32x4 acc[16];
#pragma unroll
  for (int i = 0; i < 16; ++i) acc[i] = (f32x4)0.0f;

  // staging loader: thread covers float4 f=t and f=t+256 of the 64x32 chunk
  const int r0 = t >> 3,          c40 = t & 7;
  const int r1 = (t + 256) >> 3,  c41 = (t + 256) & 7;
  const float4* rp0 = (const float4*)(raw + (size_t)(row0 + r0) * RAW_DIM) + c40;
  const float4* rp1 = (const float4*)(raw + (size_t)(row0 + r1) * RAW_DIM) + c41;
  float4 pf0 = rp0[0], pf1 = rp1[0];

  for (int ks = 0; ks < 20; ++ks) {
    __syncthreads();
    {
      bf16x4 sa; sa[0] = (short)f2bf(pf0.x); sa[1] = (short)f2bf(pf0.y);
                 sa[2] = (short)f2bf(pf0.z); sa[3] = (short)f2bf(pf0.w);
      *(bf16x4*)&As[r0][c40 * 4] = sa;
      bf16x4 sb; sb[0] = (short)f2bf(pf1.x); sb[1] = (short)f2bf(pf1.y);
                 sb[2] = (short)f2bf(pf1.z); sb[3] = (short)f2bf(pf1.w);
      *(bf16x4*)&As[r1][c41 * 4] = sb;
    }
    __syncthreads();
    if (ks < 19) { pf0 = rp0[(ks + 1) * 8]; pf1 = rp1[(ks + 1) * 8]; }

    bf16x8 a = *(const bf16x8*)&As[w * 16 + l15][quad * 8];
    const bf16x8* bp = (const bf16x8*)Wsw + (size_t)ks * 16 * 64 + lane;
#pragma unroll
    for (int ct = 0; ct < 16; ++ct) {
      bf16x8 bb = bp[(size_t)ct * 64];
      acc[ct] = __builtin_amdgcn_mfma_f32_16x16x32_bf16(a, bb, acc[ct], 0, 0, 0);
    }
  }

  // epilogue: scatter-add rows into agg[src]
  int nodes[4];
#pragma unroll
  for (int rg = 0; rg < 4; ++rg) nodes[rg] = src[row0 + w * 16 + quad * 4 + rg];
#pragma unroll
  for (int ct = 0; ct < 16; ++ct) {
    int n = ct * 16 + l15;
    float bv = bias[n];
#pragma unroll
    for (int rg = 0; rg < 4; ++rg)
      atomicAdd(&agg[(size_t)nodes[rg] * D_DIM + n], acc[ct][rg] + bv);
  }
}

// ------------- fused GRU: g = [agg/cnt, mem] @ Wbig, nonlin in-register -----
// block = 256 thr (4 waves), tile 32 rows x 1024 cols.
// wave w: rows (w>>1)*16..+16, col tiles ct = 2*i + (w&1), i=0..31
__global__ __launch_bounds__(256) void gru_fused(
    const float* __restrict__ agg, const float* __restrict__ counts,
    const uint16_t* __restrict__ Wbig_sw, const float* __restrict__ b_gru,
    const float* __restrict__ memory, float* __restrict__ out) {
  const int row0 = blockIdx.x * 32;
  __shared__ uint16_t Xs[32][520];              // 32 rows x 512 bf16, pad->520

  const int t = threadIdx.x, lane = t & 63, w = t >> 6;
  const int quad = lane >> 4, l15 = lane & 15;
  const int h = w >> 1, pp = w & 1;

  // stage X = [agg * 1/max(cnt,1) | memory] as bf16
#pragma unroll
  for (int i = 0; i < 16; ++i) {
    int f   = t + 256 * i;                      // float4 index, 0..4095
    int row = f >> 7;                           // 128 float4 per 512-col row
    int col = (f & 127) * 4;
    float4 v; float scale = 1.0f;
    if (col < 256) {
      v = *(const float4*)(agg + (size_t)(row0 + row) * D_DIM + col);
      scale = 1.0f / fmaxf(counts[row0 + row], 1.0f);
    } else {
      v = *(const float4*)(memory + (size_t)(row0 + row) * D_DIM + (col - 256));
    }
    bf16x4 s; s[0] = (short)f2bf(v.x * scale); s[1] = (short)f2bf(v.y * scale);
              s[2] = (short)f2bf(v.z * scale); s[3] = (short)f2bf(v.w * scale);
    *(bf16x4*)&Xs[row][col] = s;
  }
  __syncthreads();

  f32x4 acc[32];
#pragma unroll
  for (int i = 0; i < 32; ++i) acc[i] = (f32x4)0.0f;

  for (int ks = 0; ks < 16; ++ks) {
    bf16x8 a = *(const bf16x8*)&Xs[h * 16 + l15][ks * 32 + quad * 8];
    const bf16x8* bp = (const bf16x8*)Wbig_sw + (size_t)ks * 64 * 64 + lane;
#pragma unroll
    for (int i = 0; i < 32; ++i) {
      int ct = 2 * i + pp;
      bf16x8 bb = bp[(size_t)ct * 64];
      acc[i] = __builtin_amdgcn_mfma_f32_16x16x32_bf16(a, bb, acc[i], 0, 0, 0);
    }
  }

  // epilogue: per quadruple jt=2*ip+pp -> tiles {jt, jt+16, jt+32, jt+48}
  int   grow[4]; float cnts[4];
#pragma unroll
  for (int rg = 0; rg < 4; ++rg) {
    grow[rg] = row0 + h * 16 + quad * 4 + rg;
    cnts[rg] = counts[grow[rg]];
  }
#pragma unroll
  for (int ip = 0; ip < 8; ++ip) {
    int jt = 2 * ip + pp;
    int j  = jt * 16 + l15;                     // output col 0..255
    float b0 = b_gru[j], b1 = b_gru[256 + j], b2 = b_gru[512 + j];
#pragma unroll
    for (int rg = 0; rg < 4; ++rg) {
      float g0 = acc[ip][rg]      + b0;         // xr + hr
      float g1 = acc[ip + 8][rg]  + b1;         // xz + hz
      float g2 = acc[ip + 16][rg] + b2;         // xn
      float g3 = acc[ip + 24][rg];              // hn
      float r = 1.0f / (1.0f + __expf(-g0));
      float z = 1.0f / (1.0f + __expf(-g1));
      float nx = g2 + r * g3;
      float n = 1.0f - 2.0f / (1.0f + __expf(2.0f * nx));   // tanh(nx)
      float mv = memory[(size_t)grow[rg] * D_DIM + j];
      float hv = (1.0f - z) * n + z * mv;
      out[(size_t)grow[rg] * D_DIM + j] = (cnts[rg] > 0.0f) ? hv : mv;
    }
  }
}

// ---------------------------------------------------------------------------
extern "C" void kernel_launch(void* const* d_in, const int* in_sizes, int n_in,
                              void* d_out, int out_size, void* d_ws, size_t ws_size,
                              hipStream_t stream) {
  const float* s_raw  = (const float*)d_in[0];
  const float* d_raw  = (const float*)d_in[1];
  const int*   s_src  = (const int*)d_in[2];
  const int*   d_src  = (const int*)d_in[3];
  // d_in[4], d_in[5] = s_t, d_t (unused: t_max is dead code in the reference)
  const float* W_src  = (const float*)d_in[6];
  const float* b_src  = (const float*)d_in[7];
  const float* W_dst  = (const float*)d_in[8];
  const float* b_dst  = (const float*)d_in[9];
  const float* W_gru  = (const float*)d_in[10];
  const float* U_gru  = (const float*)d_in[11];
  const float* b_gru  = (const float*)d_in[12];
  const float* memory = (const float*)d_in[13];
  float* out = (float*)d_out;

  char* ws = (char*)d_ws;
  constexpr size_t AGG_BYTES = (size_t)N_NODES * D_DIM * 4;   // 102,400,000
  constexpr size_t CNT_BYTES = (size_t)N_NODES * 4;           //     400,000
  constexpr size_t WSW_BYTES = (size_t)20 * 16 * 64 * 8 * 2;  //     327,680
  constexpr size_t WSRC_OFF  = AGG_BYTES + CNT_BYTES;         // 16B aligned
  constexpr size_t WDST_OFF  = WSRC_OFF + WSW_BYTES;
  constexpr size_t WBIG_OFF  = WDST_OFF + WSW_BYTES;

  float*    agg     = (float*)ws;
  float*    counts  = (float*)(ws + AGG_BYTES);
  uint16_t* Wsrc_sw = (uint16_t*)(ws + WSRC_OFF);
  uint16_t* Wdst_sw = (uint16_t*)(ws + WDST_OFF);
  uint16_t* Wbig_sw = (uint16_t*)(ws + WBIG_OFF);

  // zero agg + counts (ws is poisoned 0xAA before every call)
  hipMemsetAsync(ws, 0, AGG_BYTES + CNT_BYTES, stream);

  prep_w<<<80, 256, 0, stream>>>(W_src, Wsrc_sw);
  prep_w<<<80, 256, 0, stream>>>(W_dst, Wdst_sw);
  prep_wbig<<<256, 256, 0, stream>>>(W_gru, U_gru, Wbig_sw);
  count_k<<<(2 * M_MSG + 255) / 256, 256, 0, stream>>>(s_src, d_src, counts);
  gemm_msg<<<2 * M_MSG / 64, 256, 0, stream>>>(s_raw, d_raw, s_src, d_src,
                                               Wsrc_sw, Wdst_sw, b_src, b_dst, agg);
  gru_fused<<<N_NODES / 32, 256, 0, stream>>>(agg, counts, Wbig_sw, b_gru, memory, out);
}